// Round 14
// baseline (210.439 us; speedup 1.0000x reference)
//
#include <hip/hip_runtime.h>
#include <hip/hip_bf16.h>
#include <math.h>

#define SEQ    2048
#define BATCH  2
#define DM     1024
#define NH     16
#define DH     64
#define BS_ROWS 4096
#define KDIM   1024

typedef __attribute__((ext_vector_type(8))) short short8v;
typedef __attribute__((ext_vector_type(4))) float f32x4;
typedef unsigned short ushort_t;

__device__ __forceinline__ unsigned short f2bf(float f) {
  union { float f; unsigned u; } v; v.f = f;
  unsigned r = (v.u + 0x7FFF + ((v.u >> 16) & 1)) >> 16;
  return (unsigned short)r;
}
__device__ __forceinline__ float bf2f(unsigned short h) {
  union { unsigned u; float f; } v; v.u = ((unsigned)h) << 16;
  return v.f;
}

// async global->LDS, 16B per lane; lds ptr must be wave-uniform base (+lane*16 implied)
__device__ __forceinline__ void gl16(const void* g, void* l) {
  __builtin_amdgcn_global_load_lds(
      (const __attribute__((address_space(1))) unsigned int*)g,
      (__attribute__((address_space(3))) unsigned int*)l,
      16, 0, 0);
}

// ---------------------------------------------------------------------------
// fp32 -> hi/lo bf16 split (8 elems/thread)
// ---------------------------------------------------------------------------
__global__ __launch_bounds__(256)
void split_f32(const float* __restrict__ src, ushort_t* __restrict__ h,
               ushort_t* __restrict__ l, int n8)
{
  const int i = blockIdx.x * 256 + threadIdx.x;
  if (i >= n8) return;
  const float4 v0 = ((const float4*)src)[2 * i];
  const float4 v1 = ((const float4*)src)[2 * i + 1];
  const float vals[8] = {v0.x, v0.y, v0.z, v0.w, v1.x, v1.y, v1.z, v1.w};
  short8v hv, lv;
  #pragma unroll
  for (int e = 0; e < 8; e++) {
    const unsigned short hb = f2bf(vals[e]);
    hv[e] = (short)hb;
    lv[e] = (short)f2bf(vals[e] - bf2f(hb));
  }
  ((short8v*)h)[i] = hv;
  ((short8v*)l)[i] = lv;
}

// ---------------------------------------------------------------------------
// weight transpose + split. z<=2 (qw,kw,vw): hi+lo. z==3 (ow): hi only.
// ---------------------------------------------------------------------------
__global__ __launch_bounds__(256)
void wtrans(const float* __restrict__ w0, const float* __restrict__ w1,
            const float* __restrict__ w2, const float* __restrict__ w3,
            ushort_t* __restrict__ WT)
{
  __shared__ float tile[64][65];
  const int z = blockIdx.z;
  const float* __restrict__ W = (z == 0) ? w0 : (z == 1) ? w1 : (z == 2) ? w2 : w3;
  ushort_t* __restrict__ Oh = WT + (size_t)z * 2097152;
  ushort_t* __restrict__ Ol = Oh + 1048576;

  const int n0 = blockIdx.x * 64, k0 = blockIdx.y * 64;
  const int r  = threadIdx.x >> 2;
  const int c0 = (threadIdx.x & 3) * 16;

  #pragma unroll
  for (int i = 0; i < 4; i++) {
    const float4 v = *(const float4*)&W[(size_t)(k0 + r) * KDIM + n0 + c0 + 4 * i];
    tile[r][c0 + 4 * i + 0] = v.x; tile[r][c0 + 4 * i + 1] = v.y;
    tile[r][c0 + 4 * i + 2] = v.z; tile[r][c0 + 4 * i + 3] = v.w;
  }
  __syncthreads();

  #pragma unroll
  for (int c = 0; c < 2; c++) {
    short8v hv, lv;
    #pragma unroll
    for (int e = 0; e < 8; e++) {
      const float x = tile[c0 + c * 8 + e][r];
      const unsigned short hb = f2bf(x);
      hv[e] = (short)hb;
      lv[e] = (short)f2bf(x - bf2f(hb));
    }
    const size_t off = (size_t)(n0 + r) * KDIM + k0 + c0 + c * 8;
    *(short8v*)&Oh[off] = hv;
    if (z <= 2) *(short8v*)&Ol[off] = lv;
  }
}

#define MF(a_, b_, c_) __builtin_amdgcn_mfma_f32_16x16x32_bf16(a_, b_, c_, 0, 0, 0)

#define M16(p_, q_)                                                          \
  c00=MF(p_##0,q_##0,c00); c01=MF(p_##0,q_##1,c01); c02=MF(p_##0,q_##2,c02); c03=MF(p_##0,q_##3,c03); \
  c10=MF(p_##1,q_##0,c10); c11=MF(p_##1,q_##1,c11); c12=MF(p_##1,q_##2,c12); c13=MF(p_##1,q_##3,c13); \
  c20=MF(p_##2,q_##0,c20); c21=MF(p_##2,q_##1,c21); c22=MF(p_##2,q_##2,c22); c23=MF(p_##2,q_##3,c23); \
  c30=MF(p_##3,q_##0,c30); c31=MF(p_##3,q_##1,c31); c32=MF(p_##3,q_##2,c32); c33=MF(p_##3,q_##3,c33);

// ---------------------------------------------------------------------------
// QKV GEMM, round 14: round-13 kernel (128x128, zero-conflict merged hi|lo
// swizzle, XCD-chunked block swizzle) with REGISTER-PREFETCH staging:
// load tile k+1 into named VGPRs at step-k top (latency hides under
// ds_read+MFMA), write regs->LDS after the read-complete barrier.
// Single 32KB LDS buffer -> occupancy unchanged (3 blocks/CU grid).
//   mode 0/1 (Q,K): hh + h*l + l*h -> RoPE + hi/lo split epilogue
//   mode 2   (V)  : hh + l*h       -> Vt bf16 transposed
// ---------------------------------------------------------------------------
__global__ __launch_bounds__(256, 2)
void gemm_qkv(const ushort_t* __restrict__ Ahp, const ushort_t* __restrict__ Alp,
              const ushort_t* __restrict__ WT,
              ushort_t* __restrict__ Qh, ushort_t* __restrict__ Ql,
              ushort_t* __restrict__ Kh, ushort_t* __restrict__ Kl,
              ushort_t* __restrict__ Vt)
{
  const int mode = blockIdx.z;
  const bool qk = (mode <= 1);
  const ushort_t* __restrict__ Bhp = WT + (size_t)mode * 2097152;
  const ushort_t* __restrict__ Blp = Bhp + 1048576;

  __shared__ ushort_t A2[128][64];   // 16 KB, merged hi|lo, swizzled
  __shared__ ushort_t B2[128][64];   // 16 KB

  const int t = threadIdx.x;
  const int lane = t & 63, w = t >> 6;
  const int l4 = lane & 15, lh = lane >> 4;
  const int wm = w >> 1, wn = w & 1;

  // XCD-chunked bijective swizzle (256 blocks/mode, 256 % 8 == 0)
  const int lin = blockIdx.x + (blockIdx.y << 3);
  const int sw  = ((lin & 7) << 5) + (lin >> 3);
  const int row0 = (sw >> 3) * 128, col0 = (sw & 7) * 128;

  // staging geometry (identical addressing to the gl16 version)
  const int srow = t >> 3;                 // 0..31
  const int spc  = t & 7;                  // physical chunk (LDS dest)
  const int slc  = spc ^ (srow & 7);       // logical chunk (0-3 hi, 4-7 lo)
  const int koff = (slc & 3) * 8;          // ushort offset in k-block
  const ushort_t* __restrict__ sA = (slc < 4) ? Ahp : Alp;
  const ushort_t* __restrict__ sB = (slc < 4) ? Bhp : (qk ? Blp : Bhp);

  const int pcA = lh ^ (l4 & 7);           // read-side swizzled hi chunk

  f32x4 c00 = {0,0,0,0}, c01 = {0,0,0,0}, c02 = {0,0,0,0}, c03 = {0,0,0,0};
  f32x4 c10 = {0,0,0,0}, c11 = {0,0,0,0}, c12 = {0,0,0,0}, c13 = {0,0,0,0};
  f32x4 c20 = {0,0,0,0}, c21 = {0,0,0,0}, c22 = {0,0,0,0}, c23 = {0,0,0,0};
  f32x4 c30 = {0,0,0,0}, c31 = {0,0,0,0}, c32 = {0,0,0,0}, c33 = {0,0,0,0};

  const int rA = wm * 64 + l4;
  const int rB = wn * 64 + l4;

  short8v ra0, ra1, ra2, ra3, rb0, rb1, rb2, rb3;   // prefetch regs (32 VGPR)

#define LOADR(k0_) {                                                         \
    ra0 = *(const short8v*)&sA[(size_t)(row0 +  0 + srow) * KDIM + (k0_) + koff]; \
    ra1 = *(const short8v*)&sA[(size_t)(row0 + 32 + srow) * KDIM + (k0_) + koff]; \
    ra2 = *(const short8v*)&sA[(size_t)(row0 + 64 + srow) * KDIM + (k0_) + koff]; \
    ra3 = *(const short8v*)&sA[(size_t)(row0 + 96 + srow) * KDIM + (k0_) + koff]; \
    rb0 = *(const short8v*)&sB[(size_t)(col0 +  0 + srow) * KDIM + (k0_) + koff]; \
    rb1 = *(const short8v*)&sB[(size_t)(col0 + 32 + srow) * KDIM + (k0_) + koff]; \
    rb2 = *(const short8v*)&sB[(size_t)(col0 + 64 + srow) * KDIM + (k0_) + koff]; \
    rb3 = *(const short8v*)&sB[(size_t)(col0 + 96 + srow) * KDIM + (k0_) + koff]; }

#define WRITES() {                                                           \
    *(short8v*)&A2[ 0 + srow][spc * 8] = ra0;                                \
    *(short8v*)&A2[32 + srow][spc * 8] = ra1;                                \
    *(short8v*)&A2[64 + srow][spc * 8] = ra2;                                \
    *(short8v*)&A2[96 + srow][spc * 8] = ra3;                                \
    *(short8v*)&B2[ 0 + srow][spc * 8] = rb0;                                \
    *(short8v*)&B2[32 + srow][spc * 8] = rb1;                                \
    *(short8v*)&B2[64 + srow][spc * 8] = rb2;                                \
    *(short8v*)&B2[96 + srow][spc * 8] = rb3; }

  LOADR(0); WRITES();
  __syncthreads();

  for (int kt = 0; kt < 32; kt++) {
    const bool pf = (kt + 1 < 32);
    if (pf) LOADR((kt + 1) * 32);   // issue early: latency hides under compute

    const short8v ah0 = *(const short8v*)&A2[rA +  0][pcA * 8];
    const short8v ah1 = *(const short8v*)&A2[rA + 16][pcA * 8];
    const short8v ah2 = *(const short8v*)&A2[rA + 32][pcA * 8];
    const short8v ah3 = *(const short8v*)&A2[rA + 48][pcA * 8];
    const short8v al0 = *(const short8v*)&A2[rA +  0][(pcA ^ 4) * 8];
    const short8v al1 = *(const short8v*)&A2[rA + 16][(pcA ^ 4) * 8];
    const short8v al2 = *(const short8v*)&A2[rA + 32][(pcA ^ 4) * 8];
    const short8v al3 = *(const short8v*)&A2[rA + 48][(pcA ^ 4) * 8];
    const short8v bh0 = *(const short8v*)&B2[rB +  0][pcA * 8];
    const short8v bh1 = *(const short8v*)&B2[rB + 16][pcA * 8];
    const short8v bh2 = *(const short8v*)&B2[rB + 32][pcA * 8];
    const short8v bh3 = *(const short8v*)&B2[rB + 48][pcA * 8];

    M16(ah, bh)
    if (qk) {
      const short8v bl0 = *(const short8v*)&B2[rB +  0][(pcA ^ 4) * 8];
      const short8v bl1 = *(const short8v*)&B2[rB + 16][(pcA ^ 4) * 8];
      const short8v bl2 = *(const short8v*)&B2[rB + 32][(pcA ^ 4) * 8];
      const short8v bl3 = *(const short8v*)&B2[rB + 48][(pcA ^ 4) * 8];
      M16(ah, bl)
    }
    M16(al, bh)

    __syncthreads();                // all reads of the buffer complete
    if (pf) {
      WRITES();                     // publish tile kt+1 (vmcnt waits sit here)
      __syncthreads();
    }
  }
#undef LOADR
#undef WRITES

  f32x4 acc[4][4];
  acc[0][0]=c00; acc[0][1]=c01; acc[0][2]=c02; acc[0][3]=c03;
  acc[1][0]=c10; acc[1][1]=c11; acc[1][2]=c12; acc[1][3]=c13;
  acc[2][0]=c20; acc[2][1]=c21; acc[2][2]=c22; acc[2][3]=c23;
  acc[3][0]=c30; acc[3][1]=c31; acc[3][2]=c32; acc[3][3]=c33;

  if (mode <= 1) {
    const float scale = (mode == 0) ? 0.03125f : 1.0f;
    ushort_t* __restrict__ Hp = (mode == 0) ? Qh : Kh;
    ushort_t* __restrict__ Lp = (mode == 0) ? Ql : Kl;
    #pragma unroll
    for (int mf = 0; mf < 4; mf++)
      #pragma unroll
      for (int nf = 0; nf < 4; nf++) {
        const int col = col0 + wn * 64 + nf * 16 + l4;
        const int p = (col & (DH - 1)) >> 1;
        const float fr = exp2f((float)p * -0.41524101186092030f);
        const float sgn = (col & 1) ? 1.0f : -1.0f;
        #pragma unroll
        for (int j = 0; j < 4; j++) {
          const int grow = row0 + wm * 64 + mf * 16 + lh * 4 + j;
          const float s = (float)(grow & (SEQ - 1));
          float sn, cs;
          sincosf(s * fr, &sn, &cs);
          const float val = acc[mf][nf][j];
          const float par = __shfl_xor(val, 1);
          const float out = val * cs + par * (sgn * sn);
          const float xsc = out * scale;
          const unsigned short hb = f2bf(xsc);
          Hp[(size_t)grow * DM + col] = hb;
          Lp[(size_t)grow * DM + col] = f2bf(xsc - bf2f(hb));
        }
      }
  } else {
    #pragma unroll
    for (int mf = 0; mf < 4; mf++)
      #pragma unroll
      for (int nf = 0; nf < 4; nf++) {
        const int col = col0 + wn * 64 + nf * 16 + l4;
        const int hh = col >> 6, dd = col & (DH - 1);
        #pragma unroll
        for (int j = 0; j < 4; j++) {
          const int grow = row0 + wm * 64 + mf * 16 + lh * 4 + j;
          const int b = grow >> 11, ss = grow & (SEQ - 1);
          Vt[((size_t)((b * NH + hh) * DH + dd)) * SEQ + ss] = f2bf(acc[mf][nf][j]);
        }
      }
  }
}

// ---------------------------------------------------------------------------
// Out projection: plain bf16, 128(M)x64(N) tile + XCD-chunked swizzle
// (round-13 verified, unchanged).
// ---------------------------------------------------------------------------
__global__ __launch_bounds__(256, 2)
void gemm_out(const ushort_t* __restrict__ Ahp, const ushort_t* __restrict__ WT,
              float* __restrict__ Cf)
{
  const ushort_t* __restrict__ Bhp = WT + (size_t)3 * 2097152;

  __shared__ ushort_t A3[128][32];
  __shared__ ushort_t B3[64][32];

  const int t = threadIdx.x;
  const int lane = t & 63, w = t >> 6;
  const int l4 = lane & 15, lh = lane >> 4;
  const int wm = w >> 1, wn = w & 1;

  const int lin = blockIdx.x + (blockIdx.y << 4);
  const int sw  = ((lin & 7) << 6) + (lin >> 3);
  const int row0 = (sw >> 4) * 128, col0 = (sw & 15) * 64;

  const int srow = t >> 2;
  const int spc  = t & 3;
  const int slc  = spc ^ (srow & 3);
  const int koff = slc * 8;

  const int pc4 = lh ^ (l4 & 3);

  f32x4 c00={0,0,0,0}, c01={0,0,0,0};
  f32x4 c10={0,0,0,0}, c11={0,0,0,0};
  f32x4 c20={0,0,0,0}, c21={0,0,0,0};
  f32x4 c30={0,0,0,0}, c31={0,0,0,0};

  const int rA = wm * 64 + l4;
  const int rB = wn * 32 + l4;

  for (int k0 = 0; k0 < KDIM; k0 += 32) {
    #pragma unroll
    for (int i = 0; i < 2; i++)
      gl16(Ahp + (size_t)(row0 + i * 64 + srow) * KDIM + k0 + koff,
           (char*)A3 + i * 4096 + w * 1024);
    gl16(Bhp + (size_t)(col0 + srow) * KDIM + k0 + koff,
         (char*)B3 + w * 1024);
    __syncthreads();

    const short8v ah0 = *(const short8v*)&A3[rA +  0][pc4 * 8];
    const short8v ah1 = *(const short8v*)&A3[rA + 16][pc4 * 8];
    const short8v ah2 = *(const short8v*)&A3[rA + 32][pc4 * 8];
    const short8v ah3 = *(const short8v*)&A3[rA + 48][pc4 * 8];
    const short8v bh0 = *(const short8v*)&B3[rB +  0][pc4 * 8];
    const short8v bh1 = *(const short8v*)&B3[rB + 16][pc4 * 8];

    c00 = MF(ah0, bh0, c00); c01 = MF(ah0, bh1, c01);
    c10 = MF(ah1, bh0, c10); c11 = MF(ah1, bh1, c11);
    c20 = MF(ah2, bh0, c20); c21 = MF(ah2, bh1, c21);
    c30 = MF(ah3, bh0, c30); c31 = MF(ah3, bh1, c31);
    __syncthreads();
  }

  f32x4 acc[4][2];
  acc[0][0]=c00; acc[0][1]=c01; acc[1][0]=c10; acc[1][1]=c11;
  acc[2][0]=c20; acc[2][1]=c21; acc[3][0]=c30; acc[3][1]=c31;

  #pragma unroll
  for (int mf = 0; mf < 4; mf++)
    #pragma unroll
    for (int nf = 0; nf < 2; nf++) {
      const int col = col0 + wn * 32 + nf * 16 + l4;
      #pragma unroll
      for (int j = 0; j < 4; j++) {
        const int grow = row0 + wm * 64 + mf * 16 + lh * 4 + j;
        Cf[(size_t)grow * DM + col] = acc[mf][nf][j];
      }
    }
}

// ---------------------------------------------------------------------------
// MFMA flash attention (round-7/8 structure, verified, unchanged).
// ---------------------------------------------------------------------------
__global__ __launch_bounds__(256, 4)
void attn_mfma(const ushort_t* __restrict__ Qh, const ushort_t* __restrict__ Ql,
               const ushort_t* __restrict__ Kh, const ushort_t* __restrict__ Kl,
               const ushort_t* __restrict__ Vt, ushort_t* __restrict__ AAh)
{
  __shared__ __align__(16) ushort_t Khl[2][2][64][32];
  __shared__ __align__(16) ushort_t Vtl[64][72];
  __shared__ __align__(16) ushort_t Pl[4][16][72];

  const int t = threadIdx.x;
  const int lane = t & 63, wv = t >> 6;
  const int l4 = lane & 15, lh = lane >> 4;
  const int qblk = blockIdx.x, bh = blockIdx.y;
  const int bI = bh >> 4, h = bh & 15;
  const int q0w = qblk * 64 + wv * 16;
  const int qrow = q0w + l4;

  const int kr = t >> 2, kc = t & 3;
  const int ckw = (kc ^ ((kr >> 1) & 3)) * 8;
  const int csr = (lh ^ ((l4 >> 1) & 3)) * 8;

  short8v aqh0, aqh1, aql0, aql1;
  {
    const size_t qoff = (size_t)((bI * SEQ) + qrow) * DM + h * DH;
    aqh0 = *(const short8v*)&Qh[qoff + lh * 8];
    aqh1 = *(const short8v*)&Qh[qoff + 32 + lh * 8];
    aql0 = *(const short8v*)&Ql[qoff + lh * 8];
    aql1 = *(const short8v*)&Ql[qoff + 32 + lh * 8];
  }

  f32x4 o0 = {0,0,0,0}, o1 = {0,0,0,0}, o2 = {0,0,0,0}, o3 = {0,0,0,0};
  float mrun = -1e30f, lsum = 0.f;

  const ushort_t* __restrict__ Vg = Vt + (size_t)bh * DH * SEQ;
  const size_t kgbase = (size_t)(bI * SEQ + kr) * DM + h * DH + kc * 8;
  const int nt = qblk + 1;

  short8v rkh0, rkh1, rkl0, rkl1, rv0, rv1;

#define LOADR(kt_) {                                                         \
    const size_t ko = kgbase + (size_t)(kt_) * 64 * DM;                      \
    rkh0 = *(const short8v*)&Kh[ko];                                         \
    rkh1 = *(const short8v*)&Kh[ko + 32];                                    \
    rkl0 = *(const short8v*)&Kl[ko];                                         \
    rkl1 = *(const short8v*)&Kl[ko + 32];                                    \
    const size_t vo = (size_t)kr * SEQ + (kt_) * 64 + kc * 8;                \
    rv0 = *(const short8v*)&Vg[vo];                                          \
    rv1 = *(const short8v*)&Vg[vo + 32]; }

#define WRITES() {                                                           \
    *(short8v*)&Khl[0][0][kr][ckw] = rkh0;                                   \
    *(short8v*)&Khl[0][1][kr][ckw] = rkh1;                                   \
    *(short8v*)&Khl[1][0][kr][ckw] = rkl0;                                   \
    *(short8v*)&Khl[1][1][kr][ckw] = rkl1;                                   \
    *(short8v*)&Vtl[kr][kc * 8]      = rv0;                                  \
    *(short8v*)&Vtl[kr][kc * 8 + 32] = rv1; }

#define QKSTEP(sN, n) {                                                      \
    const short8v kh0 = *(const short8v*)&Khl[0][0][(n)*16 + l4][csr];       \
    const short8v kh1 = *(const short8v*)&Khl[0][1][(n)*16 + l4][csr];       \
    const short8v kl0 = *(const short8v*)&Khl[1][0][(n)*16 + l4][csr];       \
    const short8v kl1 = *(const short8v*)&Khl[1][1][(n)*16 + l4][csr];       \
    sN = MF(kh0, aqh0, sN);                                                  \
    sN = MF(kh0, aql0, sN);                                                  \
    sN = MF(kl0, aqh0, sN);                                                  \
    sN = MF(kh1, aqh1, sN);                                                  \
    sN = MF(kh1, aql1, sN);                                                  \
    sN = MF(kl1, aqh1, sN); }

#define MASKN(sN, n) {                                                       \
    const int kb0 = kb + (n)*16 + lh*4;                                      \
    if (kb0 + 0 > qrow) sN[0] = -1e30f;                                      \
    if (kb0 + 1 > qrow) sN[1] = -1e30f;                                      \
    if (kb0 + 2 > qrow) sN[2] = -1e30f;                                      \
    if (kb0 + 3 > qrow) sN[3] = -1e30f; }

#define EXPN(sN) {                                                           \
    sN[0] = __expf(sN[0] - nm); sN[1] = __expf(sN[1] - nm);                  \
    sN[2] = __expf(sN[2] - nm); sN[3] = __expf(sN[3] - nm); }

#define PWRITE(sN, n) {                                                      \
    unsigned pa, pb;                                                         \
    asm("v_cvt_pk_bf16_f32 %0, %1, %2" : "=v"(pa) : "v"(sN[0]), "v"(sN[1]));\
    asm("v_cvt_pk_bf16_f32 %0, %1, %2" : "=v"(pb) : "v"(sN[2]), "v"(sN[3]));\
    *(unsigned*)&Pl[wv][l4][(n)*16 + lh*4]     = pa;                         \
    *(unsigned*)&Pl[wv][l4][(n)*16 + lh*4 + 2] = pb; }

#define PVSTEP(kb2) {                                                        \
    const short8v ap  = *(const short8v*)&Pl[wv][l4][(kb2)*32 + lh*8];       \
    const short8v bv0 = *(const short8v*)&Vtl[ 0 + l4][(kb2)*32 + lh*8];     \
    const short8v bv1 = *(const short8v*)&Vtl[16 + l4][(kb2)*32 + lh*8];     \
    const short8v bv2 = *(const short8v*)&Vtl[32 + l4][(kb2)*32 + lh*8];     \
    const short8v bv3 = *(const short8v*)&Vtl[48 + l4][(kb2)*32 + lh*8];     \
    o0 = MF(bv0, ap, o0);                                                    \
    o1 = MF(bv1, ap, o1);                                                    \
    o2 = MF(bv2, ap, o2);                                                    \
    o3 = MF(bv3, ap, o3); }

  LOADR(0); WRITES();
  __syncthreads();

  for (int kt = 0; kt < nt; kt++) {
    const bool pf = (kt + 1 < nt);
    if (pf) LOADR(kt + 1);

    f32x4 s0 = {0,0,0,0}, s1 = {0,0,0,0}, s2 = {0,0,0,0}, s3 = {0,0,0,0};
    QKSTEP(s0, 0) QKSTEP(s1, 1) QKSTEP(s2, 2) QKSTEP(s3, 3)

    const int kb = kt * 64;
    MASKN(s0, 0) MASKN(s1, 1) MASKN(s2, 2) MASKN(s3, 3)

    float vmax = fmaxf(fmaxf(fmaxf(s0[0], s0[1]), fmaxf(s0[2], s0[3])),
                       fmaxf(fmaxf(s1[0], s1[1]), fmaxf(s1[2], s1[3])));
    vmax = fmaxf(vmax, fmaxf(fmaxf(s2[0], s2[1]), fmaxf(s2[2], s2[3])));
    vmax = fmaxf(vmax, fmaxf(fmaxf(s3[0], s3[1]), fmaxf(s3[2], s3[3])));
    vmax = fmaxf(vmax, __shfl_xor(vmax, 16));
    vmax = fmaxf(vmax, __shfl_xor(vmax, 32));

    const float nm = fmaxf(mrun, vmax);
    const float corr = __expf(mrun - nm);
    mrun = nm;

    EXPN(s0) EXPN(s1) EXPN(s2) EXPN(s3)

    float rs = (s0[0] + s0[1]) + (s0[2] + s0[3]) + (s1[0] + s1[1]) + (s1[2] + s1[3])
             + (s2[0] + s2[1]) + (s2[2] + s2[3]) + (s3[0] + s3[1]) + (s3[2] + s3[3]);
    rs += __shfl_xor(rs, 16);
    rs += __shfl_xor(rs, 32);
    lsum = lsum * corr + rs;

    o0 *= corr; o1 *= corr; o2 *= corr; o3 *= corr;

    PWRITE(s0, 0) PWRITE(s1, 1) PWRITE(s2, 2) PWRITE(s3, 3)

    PVSTEP(0) PVSTEP(1)

    if (pf) {
      __syncthreads();
      WRITES();
      __syncthreads();
    }
  }

  const float inv = 1.0f / lsum;
  const size_t rowoff = ((size_t)(bI * SEQ + qrow)) * DM + h * DH;
  #pragma unroll
  for (int df = 0; df < 4; df++) {
    const f32x4 ov = (df == 0) ? o0 : (df == 1) ? o1 : (df == 2) ? o2 : o3;
    #pragma unroll
    for (int jp = 0; jp < 2; jp++) {
      const float x0 = ov[2 * jp] * inv;
      const float x1 = ov[2 * jp + 1] * inv;
      const unsigned short h0 = f2bf(x0), h1 = f2bf(x1);
      const size_t col = rowoff + df * 16 + lh * 4 + 2 * jp;
      *(unsigned*)&AAh[col] = (unsigned)h0 | ((unsigned)h1 << 16);
    }
  }
#undef LOADR
#undef WRITES
#undef QKSTEP
#undef MASKN
#undef EXPN
#undef PWRITE
#undef PVSTEP
}

// ---------------------------------------------------------------------------
// ws layout (56 MB):
//   0MB: Xh(8) Xl(8)      -> after QKV consumed: AAh(8) from attn
//  16MB: Kh(8) Kl(8)
//  32MB: Vt(8)
//  40MB: WT 4x(hi 2MB + lo 2MB) = 16
// d_out: Qh(8) Ql(8) scratch, then final fp32 out (16).
// ---------------------------------------------------------------------------
extern "C" void kernel_launch(void* const* d_in, const int* in_sizes, int n_in,
                              void* d_out, int out_size, void* d_ws, size_t ws_size,
                              hipStream_t stream) {
  const float* x  = (const float*)d_in[0];
  const float* qw = (const float*)d_in[1];
  const float* kw = (const float*)d_in[2];
  const float* vw = (const float*)d_in[3];
  const float* ow = (const float*)d_in[4];

  char* ws = (char*)d_ws;
  ushort_t* Xh  = (ushort_t*)ws;
  ushort_t* Xl  = Xh + 4194304;
  ushort_t* AAh = Xh;                      // Xh dead after QKV gemm
  ushort_t* Kh  = (ushort_t*)(ws + (16u << 20));
  ushort_t* Kl  = Kh + 4194304;
  ushort_t* Vt  = (ushort_t*)(ws + (32u << 20));
  ushort_t* WT  = (ushort_t*)(ws + (40u << 20));
  ushort_t* Qh  = (ushort_t*)d_out;
  ushort_t* Ql  = Qh + 4194304;
  float*    out = (float*)d_out;

  split_f32<<<dim3(2048), dim3(256), 0, stream>>>(x, Xh, Xl, 524288);
  wtrans<<<dim3(16, 16, 4), dim3(256), 0, stream>>>(qw, kw, vw, ow, WT);
  gemm_qkv<<<dim3(8, 32, 3), dim3(256), 0, stream>>>(
      Xh, Xl, WT, Qh, Ql, Kh, Kl, Vt);
  attn_mfma<<<dim3(SEQ / 64, BATCH * NH), dim3(256), 0, stream>>>(
      Qh, Ql, Kh, Kl, Vt, AAh);
  gemm_out<<<dim3(16, 32), dim3(256), 0, stream>>>(AAh, WT, out);
}

// Round 15
// 205.987 us; speedup vs baseline: 1.0216x; 1.0216x over previous
//
#include <hip/hip_runtime.h>
#include <hip/hip_bf16.h>
#include <math.h>

#define SEQ    2048
#define BATCH  2
#define DM     1024
#define NH     16
#define DH     64
#define BS_ROWS 4096
#define KDIM   1024

typedef __attribute__((ext_vector_type(8))) short short8v;
typedef __attribute__((ext_vector_type(4))) float f32x4;
typedef unsigned short ushort_t;

__device__ __forceinline__ unsigned short f2bf(float f) {
  union { float f; unsigned u; } v; v.f = f;
  unsigned r = (v.u + 0x7FFF + ((v.u >> 16) & 1)) >> 16;
  return (unsigned short)r;
}
__device__ __forceinline__ float bf2f(unsigned short h) {
  union { unsigned u; float f; } v; v.u = ((unsigned)h) << 16;
  return v.f;
}

// async global->LDS, 16B per lane; lds ptr must be wave-uniform base (+lane*16 implied)
__device__ __forceinline__ void gl16(const void* g, void* l) {
  __builtin_amdgcn_global_load_lds(
      (const __attribute__((address_space(1))) unsigned int*)g,
      (__attribute__((address_space(3))) unsigned int*)l,
      16, 0, 0);
}

// ---------------------------------------------------------------------------
// fp32 -> hi/lo bf16 split (8 elems/thread)
// ---------------------------------------------------------------------------
__global__ __launch_bounds__(256)
void split_f32(const float* __restrict__ src, ushort_t* __restrict__ h,
               ushort_t* __restrict__ l, int n8)
{
  const int i = blockIdx.x * 256 + threadIdx.x;
  if (i >= n8) return;
  const float4 v0 = ((const float4*)src)[2 * i];
  const float4 v1 = ((const float4*)src)[2 * i + 1];
  const float vals[8] = {v0.x, v0.y, v0.z, v0.w, v1.x, v1.y, v1.z, v1.w};
  short8v hv, lv;
  #pragma unroll
  for (int e = 0; e < 8; e++) {
    const unsigned short hb = f2bf(vals[e]);
    hv[e] = (short)hb;
    lv[e] = (short)f2bf(vals[e] - bf2f(hb));
  }
  ((short8v*)h)[i] = hv;
  ((short8v*)l)[i] = lv;
}

// ---------------------------------------------------------------------------
// weight transpose + split. z<=2 (qw,kw,vw): hi+lo. z==3 (ow): hi only.
// ---------------------------------------------------------------------------
__global__ __launch_bounds__(256)
void wtrans(const float* __restrict__ w0, const float* __restrict__ w1,
            const float* __restrict__ w2, const float* __restrict__ w3,
            ushort_t* __restrict__ WT)
{
  __shared__ float tile[64][65];
  const int z = blockIdx.z;
  const float* __restrict__ W = (z == 0) ? w0 : (z == 1) ? w1 : (z == 2) ? w2 : w3;
  ushort_t* __restrict__ Oh = WT + (size_t)z * 2097152;
  ushort_t* __restrict__ Ol = Oh + 1048576;

  const int n0 = blockIdx.x * 64, k0 = blockIdx.y * 64;
  const int r  = threadIdx.x >> 2;
  const int c0 = (threadIdx.x & 3) * 16;

  #pragma unroll
  for (int i = 0; i < 4; i++) {
    const float4 v = *(const float4*)&W[(size_t)(k0 + r) * KDIM + n0 + c0 + 4 * i];
    tile[r][c0 + 4 * i + 0] = v.x; tile[r][c0 + 4 * i + 1] = v.y;
    tile[r][c0 + 4 * i + 2] = v.z; tile[r][c0 + 4 * i + 3] = v.w;
  }
  __syncthreads();

  #pragma unroll
  for (int c = 0; c < 2; c++) {
    short8v hv, lv;
    #pragma unroll
    for (int e = 0; e < 8; e++) {
      const float x = tile[c0 + c * 8 + e][r];
      const unsigned short hb = f2bf(x);
      hv[e] = (short)hb;
      lv[e] = (short)f2bf(x - bf2f(hb));
    }
    const size_t off = (size_t)(n0 + r) * KDIM + k0 + c0 + c * 8;
    *(short8v*)&Oh[off] = hv;
    if (z <= 2) *(short8v*)&Ol[off] = lv;
  }
}

#define MF(a_, b_, c_) __builtin_amdgcn_mfma_f32_16x16x32_bf16(a_, b_, c_, 0, 0, 0)

#define M16(p_, q_)                                                          \
  c00=MF(p_##0,q_##0,c00); c01=MF(p_##0,q_##1,c01); c02=MF(p_##0,q_##2,c02); c03=MF(p_##0,q_##3,c03); \
  c10=MF(p_##1,q_##0,c10); c11=MF(p_##1,q_##1,c11); c12=MF(p_##1,q_##2,c12); c13=MF(p_##1,q_##3,c13); \
  c20=MF(p_##2,q_##0,c20); c21=MF(p_##2,q_##1,c21); c22=MF(p_##2,q_##2,c22); c23=MF(p_##2,q_##3,c23); \
  c30=MF(p_##3,q_##0,c30); c31=MF(p_##3,q_##1,c31); c32=MF(p_##3,q_##2,c32); c33=MF(p_##3,q_##3,c33);

// ---------------------------------------------------------------------------
// QKV GEMM: round-13 verified kernel (128x128 tile, single-buffered gl16,
// zero-conflict merged hi|lo swizzle, XCD-chunked block swizzle). Best
// measured configuration for this shape (~116us) after 5 schedule variants
// all regressed — kept verbatim.
//   mode 0/1 (Q,K): hh + h*l + l*h -> RoPE + hi/lo split epilogue
//   mode 2   (V)  : hh + l*h       -> Vt bf16 transposed
// ---------------------------------------------------------------------------
__global__ __launch_bounds__(256, 2)
void gemm_qkv(const ushort_t* __restrict__ Ahp, const ushort_t* __restrict__ Alp,
              const ushort_t* __restrict__ WT,
              ushort_t* __restrict__ Qh, ushort_t* __restrict__ Ql,
              ushort_t* __restrict__ Kh, ushort_t* __restrict__ Kl,
              ushort_t* __restrict__ Vt)
{
  const int mode = blockIdx.z;
  const bool qk = (mode <= 1);
  const ushort_t* __restrict__ Bhp = WT + (size_t)mode * 2097152;
  const ushort_t* __restrict__ Blp = Bhp + 1048576;

  __shared__ ushort_t A2[128][64];   // 16 KB, merged hi|lo, swizzled
  __shared__ ushort_t B2[128][64];   // 16 KB

  const int t = threadIdx.x;
  const int lane = t & 63, w = t >> 6;
  const int l4 = lane & 15, lh = lane >> 4;
  const int wm = w >> 1, wn = w & 1;

  // XCD-chunked bijective swizzle (256 blocks/mode, 256 % 8 == 0)
  const int lin = blockIdx.x + (blockIdx.y << 3);
  const int sw  = ((lin & 7) << 5) + (lin >> 3);
  const int row0 = (sw >> 3) * 128, col0 = (sw & 7) * 128;

  // staging: issue i covers rows i*32..i*32+31 (8 chunks/row of 16B)
  const int srow = t >> 3;                 // 0..31
  const int spc  = t & 7;                  // physical chunk
  const int slc  = spc ^ (srow & 7);       // logical chunk (0-3 hi, 4-7 lo)
  const int koff = (slc & 3) * 8;          // ushort offset in k-block
  const ushort_t* __restrict__ sA = (slc < 4) ? Ahp : Alp;
  const ushort_t* __restrict__ sB = (slc < 4) ? Bhp : (qk ? Blp : Bhp);

  const int pcA = lh ^ (l4 & 7);           // read-side swizzled hi chunk

  f32x4 c00 = {0,0,0,0}, c01 = {0,0,0,0}, c02 = {0,0,0,0}, c03 = {0,0,0,0};
  f32x4 c10 = {0,0,0,0}, c11 = {0,0,0,0}, c12 = {0,0,0,0}, c13 = {0,0,0,0};
  f32x4 c20 = {0,0,0,0}, c21 = {0,0,0,0}, c22 = {0,0,0,0}, c23 = {0,0,0,0};
  f32x4 c30 = {0,0,0,0}, c31 = {0,0,0,0}, c32 = {0,0,0,0}, c33 = {0,0,0,0};

  const int rA = wm * 64 + l4;
  const int rB = wn * 64 + l4;

  for (int k0 = 0; k0 < KDIM; k0 += 32) {
    #pragma unroll
    for (int i = 0; i < 4; i++) {
      gl16(sA + (size_t)(row0 + i * 32 + srow) * KDIM + k0 + koff,
           (char*)A2 + i * 4096 + w * 1024);
      gl16(sB + (size_t)(col0 + i * 32 + srow) * KDIM + k0 + koff,
           (char*)B2 + i * 4096 + w * 1024);
    }
    __syncthreads();

    const short8v ah0 = *(const short8v*)&A2[rA +  0][pcA * 8];
    const short8v ah1 = *(const short8v*)&A2[rA + 16][pcA * 8];
    const short8v ah2 = *(const short8v*)&A2[rA + 32][pcA * 8];
    const short8v ah3 = *(const short8v*)&A2[rA + 48][pcA * 8];
    const short8v al0 = *(const short8v*)&A2[rA +  0][(pcA ^ 4) * 8];
    const short8v al1 = *(const short8v*)&A2[rA + 16][(pcA ^ 4) * 8];
    const short8v al2 = *(const short8v*)&A2[rA + 32][(pcA ^ 4) * 8];
    const short8v al3 = *(const short8v*)&A2[rA + 48][(pcA ^ 4) * 8];
    const short8v bh0 = *(const short8v*)&B2[rB +  0][pcA * 8];
    const short8v bh1 = *(const short8v*)&B2[rB + 16][pcA * 8];
    const short8v bh2 = *(const short8v*)&B2[rB + 32][pcA * 8];
    const short8v bh3 = *(const short8v*)&B2[rB + 48][pcA * 8];

    M16(ah, bh)
    if (qk) {
      const short8v bl0 = *(const short8v*)&B2[rB +  0][(pcA ^ 4) * 8];
      const short8v bl1 = *(const short8v*)&B2[rB + 16][(pcA ^ 4) * 8];
      const short8v bl2 = *(const short8v*)&B2[rB + 32][(pcA ^ 4) * 8];
      const short8v bl3 = *(const short8v*)&B2[rB + 48][(pcA ^ 4) * 8];
      M16(ah, bl)
    }
    M16(al, bh)
    __syncthreads();
  }

  f32x4 acc[4][4];
  acc[0][0]=c00; acc[0][1]=c01; acc[0][2]=c02; acc[0][3]=c03;
  acc[1][0]=c10; acc[1][1]=c11; acc[1][2]=c12; acc[1][3]=c13;
  acc[2][0]=c20; acc[2][1]=c21; acc[2][2]=c22; acc[2][3]=c23;
  acc[3][0]=c30; acc[3][1]=c31; acc[3][2]=c32; acc[3][3]=c33;

  if (mode <= 1) {
    const float scale = (mode == 0) ? 0.03125f : 1.0f;
    ushort_t* __restrict__ Hp = (mode == 0) ? Qh : Kh;
    ushort_t* __restrict__ Lp = (mode == 0) ? Ql : Kl;
    #pragma unroll
    for (int mf = 0; mf < 4; mf++)
      #pragma unroll
      for (int nf = 0; nf < 4; nf++) {
        const int col = col0 + wn * 64 + nf * 16 + l4;
        const int p = (col & (DH - 1)) >> 1;
        const float fr = exp2f((float)p * -0.41524101186092030f);
        const float sgn = (col & 1) ? 1.0f : -1.0f;
        #pragma unroll
        for (int j = 0; j < 4; j++) {
          const int grow = row0 + wm * 64 + mf * 16 + lh * 4 + j;
          const float s = (float)(grow & (SEQ - 1));
          float sn, cs;
          sincosf(s * fr, &sn, &cs);
          const float val = acc[mf][nf][j];
          const float par = __shfl_xor(val, 1);
          const float out = val * cs + par * (sgn * sn);
          const float xsc = out * scale;
          const unsigned short hb = f2bf(xsc);
          Hp[(size_t)grow * DM + col] = hb;
          Lp[(size_t)grow * DM + col] = f2bf(xsc - bf2f(hb));
        }
      }
  } else {
    #pragma unroll
    for (int mf = 0; mf < 4; mf++)
      #pragma unroll
      for (int nf = 0; nf < 4; nf++) {
        const int col = col0 + wn * 64 + nf * 16 + l4;
        const int hh = col >> 6, dd = col & (DH - 1);
        #pragma unroll
        for (int j = 0; j < 4; j++) {
          const int grow = row0 + wm * 64 + mf * 16 + lh * 4 + j;
          const int b = grow >> 11, ss = grow & (SEQ - 1);
          Vt[((size_t)((b * NH + hh) * DH + dd)) * SEQ + ss] = f2bf(acc[mf][nf][j]);
        }
      }
  }
}

// ---------------------------------------------------------------------------
// Out projection: plain bf16, 128(M)x64(N) tile + XCD-chunked swizzle
// (round-13 verified, unchanged).
// ---------------------------------------------------------------------------
__global__ __launch_bounds__(256, 2)
void gemm_out(const ushort_t* __restrict__ Ahp, const ushort_t* __restrict__ WT,
              float* __restrict__ Cf)
{
  const ushort_t* __restrict__ Bhp = WT + (size_t)3 * 2097152;

  __shared__ ushort_t A3[128][32];
  __shared__ ushort_t B3[64][32];

  const int t = threadIdx.x;
  const int lane = t & 63, w = t >> 6;
  const int l4 = lane & 15, lh = lane >> 4;
  const int wm = w >> 1, wn = w & 1;

  const int lin = blockIdx.x + (blockIdx.y << 4);
  const int sw  = ((lin & 7) << 6) + (lin >> 3);
  const int row0 = (sw >> 4) * 128, col0 = (sw & 15) * 64;

  const int srow = t >> 2;
  const int spc  = t & 3;
  const int slc  = spc ^ (srow & 3);
  const int koff = slc * 8;

  const int pc4 = lh ^ (l4 & 3);

  f32x4 c00={0,0,0,0}, c01={0,0,0,0};
  f32x4 c10={0,0,0,0}, c11={0,0,0,0};
  f32x4 c20={0,0,0,0}, c21={0,0,0,0};
  f32x4 c30={0,0,0,0}, c31={0,0,0,0};

  const int rA = wm * 64 + l4;
  const int rB = wn * 32 + l4;

  for (int k0 = 0; k0 < KDIM; k0 += 32) {
    #pragma unroll
    for (int i = 0; i < 2; i++)
      gl16(Ahp + (size_t)(row0 + i * 64 + srow) * KDIM + k0 + koff,
           (char*)A3 + i * 4096 + w * 1024);
    gl16(Bhp + (size_t)(col0 + srow) * KDIM + k0 + koff,
         (char*)B3 + w * 1024);
    __syncthreads();

    const short8v ah0 = *(const short8v*)&A3[rA +  0][pc4 * 8];
    const short8v ah1 = *(const short8v*)&A3[rA + 16][pc4 * 8];
    const short8v ah2 = *(const short8v*)&A3[rA + 32][pc4 * 8];
    const short8v ah3 = *(const short8v*)&A3[rA + 48][pc4 * 8];
    const short8v bh0 = *(const short8v*)&B3[rB +  0][pc4 * 8];
    const short8v bh1 = *(const short8v*)&B3[rB + 16][pc4 * 8];

    c00 = MF(ah0, bh0, c00); c01 = MF(ah0, bh1, c01);
    c10 = MF(ah1, bh0, c10); c11 = MF(ah1, bh1, c11);
    c20 = MF(ah2, bh0, c20); c21 = MF(ah2, bh1, c21);
    c30 = MF(ah3, bh0, c30); c31 = MF(ah3, bh1, c31);
    __syncthreads();
  }

  f32x4 acc[4][2];
  acc[0][0]=c00; acc[0][1]=c01; acc[1][0]=c10; acc[1][1]=c11;
  acc[2][0]=c20; acc[2][1]=c21; acc[3][0]=c30; acc[3][1]=c31;

  #pragma unroll
  for (int mf = 0; mf < 4; mf++)
    #pragma unroll
    for (int nf = 0; nf < 2; nf++) {
      const int col = col0 + wn * 32 + nf * 16 + l4;
      #pragma unroll
      for (int j = 0; j < 4; j++) {
        const int grow = row0 + wm * 64 + mf * 16 + lh * 4 + j;
        Cf[(size_t)grow * DM + col] = acc[mf][nf][j];
      }
    }
}

// ---------------------------------------------------------------------------
// MFMA flash attention (round-7/8 structure, verified) + XCD-chunked block
// swizzle: XCD k owns 4 heads x all 32 qblks -> per-XCD K/V working set
// ~3MB, L2-resident; prefetch then hides ~200cy L2 hits not ~900cy HBM.
// ---------------------------------------------------------------------------
__global__ __launch_bounds__(256, 4)
void attn_mfma(const ushort_t* __restrict__ Qh, const ushort_t* __restrict__ Ql,
               const ushort_t* __restrict__ Kh, const ushort_t* __restrict__ Kl,
               const ushort_t* __restrict__ Vt, ushort_t* __restrict__ AAh)
{
  __shared__ __align__(16) ushort_t Khl[2][2][64][32];
  __shared__ __align__(16) ushort_t Vtl[64][72];
  __shared__ __align__(16) ushort_t Pl[4][16][72];

  const int t = threadIdx.x;
  const int lane = t & 63, wv = t >> 6;
  const int l4 = lane & 15, lh = lane >> 4;

  // XCD-chunked bijective swizzle (1024 blocks, 1024 % 8 == 0):
  // lin -> XCD = lin&7; XCD k owns sw in [k*128, (k+1)*128) = 4 heads x 32 qblks.
  const int lin = blockIdx.x + (blockIdx.y << 5);
  const int sw  = ((lin & 7) << 7) + (lin >> 3);
  const int qblk = sw & 31, bh = sw >> 5;

  const int bI = bh >> 4, h = bh & 15;
  const int q0w = qblk * 64 + wv * 16;
  const int qrow = q0w + l4;

  const int kr = t >> 2, kc = t & 3;
  const int ckw = (kc ^ ((kr >> 1) & 3)) * 8;
  const int csr = (lh ^ ((l4 >> 1) & 3)) * 8;

  short8v aqh0, aqh1, aql0, aql1;
  {
    const size_t qoff = (size_t)((bI * SEQ) + qrow) * DM + h * DH;
    aqh0 = *(const short8v*)&Qh[qoff + lh * 8];
    aqh1 = *(const short8v*)&Qh[qoff + 32 + lh * 8];
    aql0 = *(const short8v*)&Ql[qoff + lh * 8];
    aql1 = *(const short8v*)&Ql[qoff + 32 + lh * 8];
  }

  f32x4 o0 = {0,0,0,0}, o1 = {0,0,0,0}, o2 = {0,0,0,0}, o3 = {0,0,0,0};
  float mrun = -1e30f, lsum = 0.f;

  const ushort_t* __restrict__ Vg = Vt + (size_t)bh * DH * SEQ;
  const size_t kgbase = (size_t)(bI * SEQ + kr) * DM + h * DH + kc * 8;
  const int nt = qblk + 1;

  short8v rkh0, rkh1, rkl0, rkl1, rv0, rv1;

#define LOADR(kt_) {                                                         \
    const size_t ko = kgbase + (size_t)(kt_) * 64 * DM;                      \
    rkh0 = *(const short8v*)&Kh[ko];                                         \
    rkh1 = *(const short8v*)&Kh[ko + 32];                                    \
    rkl0 = *(const short8v*)&Kl[ko];                                         \
    rkl1 = *(const short8v*)&Kl[ko + 32];                                    \
    const size_t vo = (size_t)kr * SEQ + (kt_) * 64 + kc * 8;                \
    rv0 = *(const short8v*)&Vg[vo];                                          \
    rv1 = *(const short8v*)&Vg[vo + 32]; }

#define WRITES() {                                                           \
    *(short8v*)&Khl[0][0][kr][ckw] = rkh0;                                   \
    *(short8v*)&Khl[0][1][kr][ckw] = rkh1;                                   \
    *(short8v*)&Khl[1][0][kr][ckw] = rkl0;                                   \
    *(short8v*)&Khl[1][1][kr][ckw] = rkl1;                                   \
    *(short8v*)&Vtl[kr][kc * 8]      = rv0;                                  \
    *(short8v*)&Vtl[kr][kc * 8 + 32] = rv1; }

#define QKSTEP(sN, n) {                                                      \
    const short8v kh0 = *(const short8v*)&Khl[0][0][(n)*16 + l4][csr];       \
    const short8v kh1 = *(const short8v*)&Khl[0][1][(n)*16 + l4][csr];       \
    const short8v kl0 = *(const short8v*)&Khl[1][0][(n)*16 + l4][csr];       \
    const short8v kl1 = *(const short8v*)&Khl[1][1][(n)*16 + l4][csr];       \
    sN = MF(kh0, aqh0, sN);                                                  \
    sN = MF(kh0, aql0, sN);                                                  \
    sN = MF(kl0, aqh0, sN);                                                  \
    sN = MF(kh1, aqh1, sN);                                                  \
    sN = MF(kh1, aql1, sN);                                                  \
    sN = MF(kl1, aqh1, sN); }

#define MASKN(sN, n) {                                                       \
    const int kb0 = kb + (n)*16 + lh*4;                                      \
    if (kb0 + 0 > qrow) sN[0] = -1e30f;                                      \
    if (kb0 + 1 > qrow) sN[1] = -1e30f;                                      \
    if (kb0 + 2 > qrow) sN[2] = -1e30f;                                      \
    if (kb0 + 3 > qrow) sN[3] = -1e30f; }

#define EXPN(sN) {                                                           \
    sN[0] = __expf(sN[0] - nm); sN[1] = __expf(sN[1] - nm);                  \
    sN[2] = __expf(sN[2] - nm); sN[3] = __expf(sN[3] - nm); }

#define PWRITE(sN, n) {                                                      \
    unsigned pa, pb;                                                         \
    asm("v_cvt_pk_bf16_f32 %0, %1, %2" : "=v"(pa) : "v"(sN[0]), "v"(sN[1]));\
    asm("v_cvt_pk_bf16_f32 %0, %1, %2" : "=v"(pb) : "v"(sN[2]), "v"(sN[3]));\
    *(unsigned*)&Pl[wv][l4][(n)*16 + lh*4]     = pa;                         \
    *(unsigned*)&Pl[wv][l4][(n)*16 + lh*4 + 2] = pb; }

#define PVSTEP(kb2) {                                                        \
    const short8v ap  = *(const short8v*)&Pl[wv][l4][(kb2)*32 + lh*8];       \
    const short8v bv0 = *(const short8v*)&Vtl[ 0 + l4][(kb2)*32 + lh*8];     \
    const short8v bv1 = *(const short8v*)&Vtl[16 + l4][(kb2)*32 + lh*8];     \
    const short8v bv2 = *(const short8v*)&Vtl[32 + l4][(kb2)*32 + lh*8];     \
    const short8v bv3 = *(const short8v*)&Vtl[48 + l4][(kb2)*32 + lh*8];     \
    o0 = MF(bv0, ap, o0);                                                    \
    o1 = MF(bv1, ap, o1);                                                    \
    o2 = MF(bv2, ap, o2);                                                    \
    o3 = MF(bv3, ap, o3); }

  LOADR(0); WRITES();
  __syncthreads();

  for (int kt = 0; kt < nt; kt++) {
    const bool pf = (kt + 1 < nt);
    if (pf) LOADR(kt + 1);

    f32x4 s0 = {0,0,0,0}, s1 = {0,0,0,0}, s2 = {0,0,0,0}, s3 = {0,0,0,0};
    QKSTEP(s0, 0) QKSTEP(s1, 1) QKSTEP(s2, 2) QKSTEP(s3, 3)

    const int kb = kt * 64;
    MASKN(s0, 0) MASKN(s1, 1) MASKN(s2, 2) MASKN(s3, 3)

    float vmax = fmaxf(fmaxf(fmaxf(s0[0], s0[1]), fmaxf(s0[2], s0[3])),
                       fmaxf(fmaxf(s1[0], s1[1]), fmaxf(s1[2], s1[3])));
    vmax = fmaxf(vmax, fmaxf(fmaxf(s2[0], s2[1]), fmaxf(s2[2], s2[3])));
    vmax = fmaxf(vmax, fmaxf(fmaxf(s3[0], s3[1]), fmaxf(s3[2], s3[3])));
    vmax = fmaxf(vmax, __shfl_xor(vmax, 16));
    vmax = fmaxf(vmax, __shfl_xor(vmax, 32));

    const float nm = fmaxf(mrun, vmax);
    const float corr = __expf(mrun - nm);
    mrun = nm;

    EXPN(s0) EXPN(s1) EXPN(s2) EXPN(s3)

    float rs = (s0[0] + s0[1]) + (s0[2] + s0[3]) + (s1[0] + s1[1]) + (s1[2] + s1[3])
             + (s2[0] + s2[1]) + (s2[2] + s2[3]) + (s3[0] + s3[1]) + (s3[2] + s3[3]);
    rs += __shfl_xor(rs, 16);
    rs += __shfl_xor(rs, 32);
    lsum = lsum * corr + rs;

    o0 *= corr; o1 *= corr; o2 *= corr; o3 *= corr;

    PWRITE(s0, 0) PWRITE(s1, 1) PWRITE(s2, 2) PWRITE(s3, 3)

    PVSTEP(0) PVSTEP(1)

    if (pf) {
      __syncthreads();
      WRITES();
      __syncthreads();
    }
  }

  const float inv = 1.0f / lsum;
  const size_t rowoff = ((size_t)(bI * SEQ + qrow)) * DM + h * DH;
  #pragma unroll
  for (int df = 0; df < 4; df++) {
    const f32x4 ov = (df == 0) ? o0 : (df == 1) ? o1 : (df == 2) ? o2 : o3;
    #pragma unroll
    for (int jp = 0; jp < 2; jp++) {
      const float x0 = ov[2 * jp] * inv;
      const float x1 = ov[2 * jp + 1] * inv;
      const unsigned short h0 = f2bf(x0), h1 = f2bf(x1);
      const size_t col = rowoff + df * 16 + lh * 4 + 2 * jp;
      *(unsigned*)&AAh[col] = (unsigned)h0 | ((unsigned)h1 << 16);
    }
  }
#undef LOADR
#undef WRITES
#undef QKSTEP
#undef MASKN
#undef EXPN
#undef PWRITE
#undef PVSTEP
}

// ---------------------------------------------------------------------------
// ws layout (56 MB):
//   0MB: Xh(8) Xl(8)      -> after QKV consumed: AAh(8) from attn
//  16MB: Kh(8) Kl(8)
//  32MB: Vt(8)
//  40MB: WT 4x(hi 2MB + lo 2MB) = 16
// d_out: Qh(8) Ql(8) scratch, then final fp32 out (16).
// ---------------------------------------------------------------------------
extern "C" void kernel_launch(void* const* d_in, const int* in_sizes, int n_in,
                              void* d_out, int out_size, void* d_ws, size_t ws_size,
                              hipStream_t stream) {
  const float* x  = (const float*)d_in[0];
  const float* qw = (const float*)d_in[1];
  const float* kw = (const float*)d_in[2];
  const float* vw = (const float*)d_in[3];
  const float* ow = (const float*)d_in[4];

  char* ws = (char*)d_ws;
  ushort_t* Xh  = (ushort_t*)ws;
  ushort_t* Xl  = Xh + 4194304;
  ushort_t* AAh = Xh;                      // Xh dead after QKV gemm
  ushort_t* Kh  = (ushort_t*)(ws + (16u << 20));
  ushort_t* Kl  = Kh + 4194304;
  ushort_t* Vt  = (ushort_t*)(ws + (32u << 20));
  ushort_t* WT  = (ushort_t*)(ws + (40u << 20));
  ushort_t* Qh  = (ushort_t*)d_out;
  ushort_t* Ql  = Qh + 4194304;
  float*    out = (float*)d_out;

  split_f32<<<dim3(2048), dim3(256), 0, stream>>>(x, Xh, Xl, 524288);
  wtrans<<<dim3(16, 16, 4), dim3(256), 0, stream>>>(qw, kw, vw, ow, WT);
  gemm_qkv<<<dim3(8, 32, 3), dim3(256), 0, stream>>>(
      Xh, Xl, WT, Qh, Ql, Kh, Kl, Vt);
  attn_mfma<<<dim3(SEQ / 64, BATCH * NH), dim3(256), 0, stream>>>(
      Qh, Ql, Kh, Kl, Vt, AAh);
  gemm_out<<<dim3(16, 32), dim3(256), 0, stream>>>(AAh, WT, out);
}

// Round 16
// 198.797 us; speedup vs baseline: 1.0586x; 1.0362x over previous
//
#include <hip/hip_runtime.h>
#include <hip/hip_bf16.h>
#include <math.h>

#define SEQ    2048
#define BATCH  2
#define DM     1024
#define NH     16
#define DH     64
#define BS_ROWS 4096
#define KDIM   1024

typedef __attribute__((ext_vector_type(8))) short short8v;
typedef __attribute__((ext_vector_type(4))) float f32x4;
typedef unsigned short ushort_t;

__device__ __forceinline__ unsigned short f2bf(float f) {
  union { float f; unsigned u; } v; v.f = f;
  unsigned r = (v.u + 0x7FFF + ((v.u >> 16) & 1)) >> 16;
  return (unsigned short)r;
}
__device__ __forceinline__ float bf2f(unsigned short h) {
  union { unsigned u; float f; } v; v.u = ((unsigned)h) << 16;
  return v.f;
}

// async global->LDS, 16B per lane; lds ptr must be wave-uniform base (+lane*16 implied)
__device__ __forceinline__ void gl16(const void* g, void* l) {
  __builtin_amdgcn_global_load_lds(
      (const __attribute__((address_space(1))) unsigned int*)g,
      (__attribute__((address_space(3))) unsigned int*)l,
      16, 0, 0);
}

// ---------------------------------------------------------------------------
// fp32 -> hi/lo bf16 split (8 elems/thread)
// ---------------------------------------------------------------------------
__global__ __launch_bounds__(256)
void split_f32(const float* __restrict__ src, ushort_t* __restrict__ h,
               ushort_t* __restrict__ l, int n8)
{
  const int i = blockIdx.x * 256 + threadIdx.x;
  if (i >= n8) return;
  const float4 v0 = ((const float4*)src)[2 * i];
  const float4 v1 = ((const float4*)src)[2 * i + 1];
  const float vals[8] = {v0.x, v0.y, v0.z, v0.w, v1.x, v1.y, v1.z, v1.w};
  short8v hv, lv;
  #pragma unroll
  for (int e = 0; e < 8; e++) {
    const unsigned short hb = f2bf(vals[e]);
    hv[e] = (short)hb;
    lv[e] = (short)f2bf(vals[e] - bf2f(hb));
  }
  ((short8v*)h)[i] = hv;
  ((short8v*)l)[i] = lv;
}

// ---------------------------------------------------------------------------
// weight transpose + split. z<=1 (qw,kw): hi+lo. z>=2 (vw,ow): hi only
// (V is now plain bf16: 1 MFMA term).
// ---------------------------------------------------------------------------
__global__ __launch_bounds__(256)
void wtrans(const float* __restrict__ w0, const float* __restrict__ w1,
            const float* __restrict__ w2, const float* __restrict__ w3,
            ushort_t* __restrict__ WT)
{
  __shared__ float tile[64][65];
  const int z = blockIdx.z;
  const float* __restrict__ W = (z == 0) ? w0 : (z == 1) ? w1 : (z == 2) ? w2 : w3;
  ushort_t* __restrict__ Oh = WT + (size_t)z * 2097152;
  ushort_t* __restrict__ Ol = Oh + 1048576;

  const int n0 = blockIdx.x * 64, k0 = blockIdx.y * 64;
  const int r  = threadIdx.x >> 2;
  const int c0 = (threadIdx.x & 3) * 16;

  #pragma unroll
  for (int i = 0; i < 4; i++) {
    const float4 v = *(const float4*)&W[(size_t)(k0 + r) * KDIM + n0 + c0 + 4 * i];
    tile[r][c0 + 4 * i + 0] = v.x; tile[r][c0 + 4 * i + 1] = v.y;
    tile[r][c0 + 4 * i + 2] = v.z; tile[r][c0 + 4 * i + 3] = v.w;
  }
  __syncthreads();

  #pragma unroll
  for (int c = 0; c < 2; c++) {
    short8v hv, lv;
    #pragma unroll
    for (int e = 0; e < 8; e++) {
      const float x = tile[c0 + c * 8 + e][r];
      const unsigned short hb = f2bf(x);
      hv[e] = (short)hb;
      lv[e] = (short)f2bf(x - bf2f(hb));
    }
    const size_t off = (size_t)(n0 + r) * KDIM + k0 + c0 + c * 8;
    *(short8v*)&Oh[off] = hv;
    if (z <= 1) *(short8v*)&Ol[off] = lv;
  }
}

#define MF(a_, b_, c_) __builtin_amdgcn_mfma_f32_16x16x32_bf16(a_, b_, c_, 0, 0, 0)

#define M16(p_, q_)                                                          \
  c00=MF(p_##0,q_##0,c00); c01=MF(p_##0,q_##1,c01); c02=MF(p_##0,q_##2,c02); c03=MF(p_##0,q_##3,c03); \
  c10=MF(p_##1,q_##0,c10); c11=MF(p_##1,q_##1,c11); c12=MF(p_##1,q_##2,c12); c13=MF(p_##1,q_##3,c13); \
  c20=MF(p_##2,q_##0,c20); c21=MF(p_##2,q_##1,c21); c22=MF(p_##2,q_##2,c22); c23=MF(p_##2,q_##3,c23); \
  c30=MF(p_##3,q_##0,c30); c31=MF(p_##3,q_##1,c31); c32=MF(p_##3,q_##2,c32); c33=MF(p_##3,q_##3,c33);

// ---------------------------------------------------------------------------
// QKV GEMM: round-13 verified structure (128x128 tile, single-buffered gl16,
// zero-conflict merged hi|lo swizzle, XCD-chunked block swizzle).
//   mode 0/1 (Q,K): hh + h*l + l*h (3 terms) -> RoPE + hi/lo split epilogue
//   mode 2   (V)  : hh only (1 term; error budget round 16) -> Vt bf16
//                   transposed. Mode 2 skips lo staging + lo LDS reads.
// ---------------------------------------------------------------------------
__global__ __launch_bounds__(256, 2)
void gemm_qkv(const ushort_t* __restrict__ Ahp, const ushort_t* __restrict__ Alp,
              const ushort_t* __restrict__ WT,
              ushort_t* __restrict__ Qh, ushort_t* __restrict__ Ql,
              ushort_t* __restrict__ Kh, ushort_t* __restrict__ Kl,
              ushort_t* __restrict__ Vt)
{
  const int mode = blockIdx.z;
  const bool qk = (mode <= 1);
  const ushort_t* __restrict__ Bhp = WT + (size_t)mode * 2097152;
  const ushort_t* __restrict__ Blp = Bhp + 1048576;

  __shared__ ushort_t A2[128][64];   // 16 KB, merged hi|lo, swizzled
  __shared__ ushort_t B2[128][64];   // 16 KB

  const int t = threadIdx.x;
  const int lane = t & 63, w = t >> 6;
  const int l4 = lane & 15, lh = lane >> 4;
  const int wm = w >> 1, wn = w & 1;

  // XCD-chunked bijective swizzle (256 blocks/mode, 256 % 8 == 0)
  const int lin = blockIdx.x + (blockIdx.y << 3);
  const int sw  = ((lin & 7) << 5) + (lin >> 3);
  const int row0 = (sw >> 3) * 128, col0 = (sw & 7) * 128;

  // staging: issue i covers rows i*32..i*32+31 (8 chunks/row of 16B)
  const int srow = t >> 3;                 // 0..31
  const int spc  = t & 7;                  // physical chunk
  const int slc  = spc ^ (srow & 7);       // logical chunk (0-3 hi, 4-7 lo)
  const int koff = (slc & 3) * 8;          // ushort offset in k-block
  const ushort_t* __restrict__ sA = (slc < 4) ? Ahp : Alp;
  const ushort_t* __restrict__ sB = (slc < 4) ? Bhp : (qk ? Blp : Bhp);

  const int pcA = lh ^ (l4 & 7);           // read-side swizzled hi chunk

  f32x4 c00 = {0,0,0,0}, c01 = {0,0,0,0}, c02 = {0,0,0,0}, c03 = {0,0,0,0};
  f32x4 c10 = {0,0,0,0}, c11 = {0,0,0,0}, c12 = {0,0,0,0}, c13 = {0,0,0,0};
  f32x4 c20 = {0,0,0,0}, c21 = {0,0,0,0}, c22 = {0,0,0,0}, c23 = {0,0,0,0};
  f32x4 c30 = {0,0,0,0}, c31 = {0,0,0,0}, c32 = {0,0,0,0}, c33 = {0,0,0,0};

  const int rA = wm * 64 + l4;
  const int rB = wn * 64 + l4;

  const bool stageMe = qk || (slc < 4);    // mode 2: lo half never read

  for (int k0 = 0; k0 < KDIM; k0 += 32) {
    if (stageMe) {
      #pragma unroll
      for (int i = 0; i < 4; i++) {
        gl16(sA + (size_t)(row0 + i * 32 + srow) * KDIM + k0 + koff,
             (char*)A2 + i * 4096 + w * 1024);
        gl16(sB + (size_t)(col0 + i * 32 + srow) * KDIM + k0 + koff,
             (char*)B2 + i * 4096 + w * 1024);
      }
    }
    __syncthreads();

    const short8v ah0 = *(const short8v*)&A2[rA +  0][pcA * 8];
    const short8v ah1 = *(const short8v*)&A2[rA + 16][pcA * 8];
    const short8v ah2 = *(const short8v*)&A2[rA + 32][pcA * 8];
    const short8v ah3 = *(const short8v*)&A2[rA + 48][pcA * 8];
    const short8v bh0 = *(const short8v*)&B2[rB +  0][pcA * 8];
    const short8v bh1 = *(const short8v*)&B2[rB + 16][pcA * 8];
    const short8v bh2 = *(const short8v*)&B2[rB + 32][pcA * 8];
    const short8v bh3 = *(const short8v*)&B2[rB + 48][pcA * 8];

    M16(ah, bh)
    if (qk) {
      const short8v al0 = *(const short8v*)&A2[rA +  0][(pcA ^ 4) * 8];
      const short8v al1 = *(const short8v*)&A2[rA + 16][(pcA ^ 4) * 8];
      const short8v al2 = *(const short8v*)&A2[rA + 32][(pcA ^ 4) * 8];
      const short8v al3 = *(const short8v*)&A2[rA + 48][(pcA ^ 4) * 8];
      const short8v bl0 = *(const short8v*)&B2[rB +  0][(pcA ^ 4) * 8];
      const short8v bl1 = *(const short8v*)&B2[rB + 16][(pcA ^ 4) * 8];
      const short8v bl2 = *(const short8v*)&B2[rB + 32][(pcA ^ 4) * 8];
      const short8v bl3 = *(const short8v*)&B2[rB + 48][(pcA ^ 4) * 8];
      M16(ah, bl)
      M16(al, bh)
    }
    __syncthreads();
  }

  f32x4 acc[4][4];
  acc[0][0]=c00; acc[0][1]=c01; acc[0][2]=c02; acc[0][3]=c03;
  acc[1][0]=c10; acc[1][1]=c11; acc[1][2]=c12; acc[1][3]=c13;
  acc[2][0]=c20; acc[2][1]=c21; acc[2][2]=c22; acc[2][3]=c23;
  acc[3][0]=c30; acc[3][1]=c31; acc[3][2]=c32; acc[3][3]=c33;

  if (mode <= 1) {
    const float scale = (mode == 0) ? 0.03125f : 1.0f;
    ushort_t* __restrict__ Hp = (mode == 0) ? Qh : Kh;
    ushort_t* __restrict__ Lp = (mode == 0) ? Ql : Kl;
    #pragma unroll
    for (int mf = 0; mf < 4; mf++)
      #pragma unroll
      for (int nf = 0; nf < 4; nf++) {
        const int col = col0 + wn * 64 + nf * 16 + l4;
        const int p = (col & (DH - 1)) >> 1;
        const float fr = exp2f((float)p * -0.41524101186092030f);
        const float sgn = (col & 1) ? 1.0f : -1.0f;
        #pragma unroll
        for (int j = 0; j < 4; j++) {
          const int grow = row0 + wm * 64 + mf * 16 + lh * 4 + j;
          const float s = (float)(grow & (SEQ - 1));
          float sn, cs;
          sincosf(s * fr, &sn, &cs);
          const float val = acc[mf][nf][j];
          const float par = __shfl_xor(val, 1);
          const float out = val * cs + par * (sgn * sn);
          const float xsc = out * scale;
          const unsigned short hb = f2bf(xsc);
          Hp[(size_t)grow * DM + col] = hb;
          Lp[(size_t)grow * DM + col] = f2bf(xsc - bf2f(hb));
        }
      }
  } else {
    #pragma unroll
    for (int mf = 0; mf < 4; mf++)
      #pragma unroll
      for (int nf = 0; nf < 4; nf++) {
        const int col = col0 + wn * 64 + nf * 16 + l4;
        const int hh = col >> 6, dd = col & (DH - 1);
        #pragma unroll
        for (int j = 0; j < 4; j++) {
          const int grow = row0 + wm * 64 + mf * 16 + lh * 4 + j;
          const int b = grow >> 11, ss = grow & (SEQ - 1);
          Vt[((size_t)((b * NH + hh) * DH + dd)) * SEQ + ss] = f2bf(acc[mf][nf][j]);
        }
      }
  }
}

// ---------------------------------------------------------------------------
// Out projection: plain bf16, 128(M)x64(N) tile + XCD-chunked swizzle
// (round-13 verified, unchanged).
// ---------------------------------------------------------------------------
__global__ __launch_bounds__(256, 2)
void gemm_out(const ushort_t* __restrict__ Ahp, const ushort_t* __restrict__ WT,
              float* __restrict__ Cf)
{
  const ushort_t* __restrict__ Bhp = WT + (size_t)3 * 2097152;

  __shared__ ushort_t A3[128][32];
  __shared__ ushort_t B3[64][32];

  const int t = threadIdx.x;
  const int lane = t & 63, w = t >> 6;
  const int l4 = lane & 15, lh = lane >> 4;
  const int wm = w >> 1, wn = w & 1;

  const int lin = blockIdx.x + (blockIdx.y << 4);
  const int sw  = ((lin & 7) << 6) + (lin >> 3);
  const int row0 = (sw >> 4) * 128, col0 = (sw & 15) * 64;

  const int srow = t >> 2;
  const int spc  = t & 3;
  const int slc  = spc ^ (srow & 3);
  const int koff = slc * 8;

  const int pc4 = lh ^ (l4 & 3);

  f32x4 c00={0,0,0,0}, c01={0,0,0,0};
  f32x4 c10={0,0,0,0}, c11={0,0,0,0};
  f32x4 c20={0,0,0,0}, c21={0,0,0,0};
  f32x4 c30={0,0,0,0}, c31={0,0,0,0};

  const int rA = wm * 64 + l4;
  const int rB = wn * 32 + l4;

  for (int k0 = 0; k0 < KDIM; k0 += 32) {
    #pragma unroll
    for (int i = 0; i < 2; i++)
      gl16(Ahp + (size_t)(row0 + i * 64 + srow) * KDIM + k0 + koff,
           (char*)A3 + i * 4096 + w * 1024);
    gl16(Bhp + (size_t)(col0 + srow) * KDIM + k0 + koff,
         (char*)B3 + w * 1024);
    __syncthreads();

    const short8v ah0 = *(const short8v*)&A3[rA +  0][pc4 * 8];
    const short8v ah1 = *(const short8v*)&A3[rA + 16][pc4 * 8];
    const short8v ah2 = *(const short8v*)&A3[rA + 32][pc4 * 8];
    const short8v ah3 = *(const short8v*)&A3[rA + 48][pc4 * 8];
    const short8v bh0 = *(const short8v*)&B3[rB +  0][pc4 * 8];
    const short8v bh1 = *(const short8v*)&B3[rB + 16][pc4 * 8];

    c00 = MF(ah0, bh0, c00); c01 = MF(ah0, bh1, c01);
    c10 = MF(ah1, bh0, c10); c11 = MF(ah1, bh1, c11);
    c20 = MF(ah2, bh0, c20); c21 = MF(ah2, bh1, c21);
    c30 = MF(ah3, bh0, c30); c31 = MF(ah3, bh1, c31);
    __syncthreads();
  }

  f32x4 acc[4][2];
  acc[0][0]=c00; acc[0][1]=c01; acc[1][0]=c10; acc[1][1]=c11;
  acc[2][0]=c20; acc[2][1]=c21; acc[3][0]=c30; acc[3][1]=c31;

  #pragma unroll
  for (int mf = 0; mf < 4; mf++)
    #pragma unroll
    for (int nf = 0; nf < 2; nf++) {
      const int col = col0 + wn * 32 + nf * 16 + l4;
      #pragma unroll
      for (int j = 0; j < 4; j++) {
        const int grow = row0 + wm * 64 + mf * 16 + lh * 4 + j;
        Cf[(size_t)grow * DM + col] = acc[mf][nf][j];
      }
    }
}

// ---------------------------------------------------------------------------
// MFMA flash attention (round-15 structure: XCD swizzle, reg prefetch,
// swizzled K) + defer-max (T13): skip O-rescale when tile max grows <= 8.
// ---------------------------------------------------------------------------
__global__ __launch_bounds__(256, 4)
void attn_mfma(const ushort_t* __restrict__ Qh, const ushort_t* __restrict__ Ql,
               const ushort_t* __restrict__ Kh, const ushort_t* __restrict__ Kl,
               const ushort_t* __restrict__ Vt, ushort_t* __restrict__ AAh)
{
  __shared__ __align__(16) ushort_t Khl[2][2][64][32];
  __shared__ __align__(16) ushort_t Vtl[64][72];
  __shared__ __align__(16) ushort_t Pl[4][16][72];

  const int t = threadIdx.x;
  const int lane = t & 63, wv = t >> 6;
  const int l4 = lane & 15, lh = lane >> 4;

  // XCD-chunked bijective swizzle (1024 blocks, 1024 % 8 == 0)
  const int lin = blockIdx.x + (blockIdx.y << 5);
  const int sw  = ((lin & 7) << 7) + (lin >> 3);
  const int qblk = sw & 31, bh = sw >> 5;

  const int bI = bh >> 4, h = bh & 15;
  const int q0w = qblk * 64 + wv * 16;
  const int qrow = q0w + l4;

  const int kr = t >> 2, kc = t & 3;
  const int ckw = (kc ^ ((kr >> 1) & 3)) * 8;
  const int csr = (lh ^ ((l4 >> 1) & 3)) * 8;

  short8v aqh0, aqh1, aql0, aql1;
  {
    const size_t qoff = (size_t)((bI * SEQ) + qrow) * DM + h * DH;
    aqh0 = *(const short8v*)&Qh[qoff + lh * 8];
    aqh1 = *(const short8v*)&Qh[qoff + 32 + lh * 8];
    aql0 = *(const short8v*)&Ql[qoff + lh * 8];
    aql1 = *(const short8v*)&Ql[qoff + 32 + lh * 8];
  }

  f32x4 o0 = {0,0,0,0}, o1 = {0,0,0,0}, o2 = {0,0,0,0}, o3 = {0,0,0,0};
  float mrun = -1e30f, lsum = 0.f;

  const ushort_t* __restrict__ Vg = Vt + (size_t)bh * DH * SEQ;
  const size_t kgbase = (size_t)(bI * SEQ + kr) * DM + h * DH + kc * 8;
  const int nt = qblk + 1;

  short8v rkh0, rkh1, rkl0, rkl1, rv0, rv1;

#define LOADR(kt_) {                                                         \
    const size_t ko = kgbase + (size_t)(kt_) * 64 * DM;                      \
    rkh0 = *(const short8v*)&Kh[ko];                                         \
    rkh1 = *(const short8v*)&Kh[ko + 32];                                    \
    rkl0 = *(const short8v*)&Kl[ko];                                         \
    rkl1 = *(const short8v*)&Kl[ko + 32];                                    \
    const size_t vo = (size_t)kr * SEQ + (kt_) * 64 + kc * 8;                \
    rv0 = *(const short8v*)&Vg[vo];                                          \
    rv1 = *(const short8v*)&Vg[vo + 32]; }

#define WRITES() {                                                           \
    *(short8v*)&Khl[0][0][kr][ckw] = rkh0;                                   \
    *(short8v*)&Khl[0][1][kr][ckw] = rkh1;                                   \
    *(short8v*)&Khl[1][0][kr][ckw] = rkl0;                                   \
    *(short8v*)&Khl[1][1][kr][ckw] = rkl1;                                   \
    *(short8v*)&Vtl[kr][kc * 8]      = rv0;                                  \
    *(short8v*)&Vtl[kr][kc * 8 + 32] = rv1; }

#define QKSTEP(sN, n) {                                                      \
    const short8v kh0 = *(const short8v*)&Khl[0][0][(n)*16 + l4][csr];       \
    const short8v kh1 = *(const short8v*)&Khl[0][1][(n)*16 + l4][csr];       \
    const short8v kl0 = *(const short8v*)&Khl[1][0][(n)*16 + l4][csr];       \
    const short8v kl1 = *(const short8v*)&Khl[1][1][(n)*16 + l4][csr];       \
    sN = MF(kh0, aqh0, sN);                                                  \
    sN = MF(kh0, aql0, sN);                                                  \
    sN = MF(kl0, aqh0, sN);                                                  \
    sN = MF(kh1, aqh1, sN);                                                  \
    sN = MF(kh1, aql1, sN);                                                  \
    sN = MF(kl1, aqh1, sN); }

#define MASKN(sN, n) {                                                       \
    const int kb0 = kb + (n)*16 + lh*4;                                      \
    if (kb0 + 0 > qrow) sN[0] = -1e30f;                                      \
    if (kb0 + 1 > qrow) sN[1] = -1e30f;                                      \
    if (kb0 + 2 > qrow) sN[2] = -1e30f;                                      \
    if (kb0 + 3 > qrow) sN[3] = -1e30f; }

#define EXPN(sN) {                                                           \
    sN[0] = __expf(sN[0] - nm); sN[1] = __expf(sN[1] - nm);                  \
    sN[2] = __expf(sN[2] - nm); sN[3] = __expf(sN[3] - nm); }

#define PWRITE(sN, n) {                                                      \
    unsigned pa, pb;                                                         \
    asm("v_cvt_pk_bf16_f32 %0, %1, %2" : "=v"(pa) : "v"(sN[0]), "v"(sN[1]));\
    asm("v_cvt_pk_bf16_f32 %0, %1, %2" : "=v"(pb) : "v"(sN[2]), "v"(sN[3]));\
    *(unsigned*)&Pl[wv][l4][(n)*16 + lh*4]     = pa;                         \
    *(unsigned*)&Pl[wv][l4][(n)*16 + lh*4 + 2] = pb; }

#define PVSTEP(kb2) {                                                        \
    const short8v ap  = *(const short8v*)&Pl[wv][l4][(kb2)*32 + lh*8];       \
    const short8v bv0 = *(const short8v*)&Vtl[ 0 + l4][(kb2)*32 + lh*8];     \
    const short8v bv1 = *(const short8v*)&Vtl[16 + l4][(kb2)*32 + lh*8];     \
    const short8v bv2 = *(const short8v*)&Vtl[32 + l4][(kb2)*32 + lh*8];     \
    const short8v bv3 = *(const short8v*)&Vtl[48 + l4][(kb2)*32 + lh*8];     \
    o0 = MF(bv0, ap, o0);                                                    \
    o1 = MF(bv1, ap, o1);                                                    \
    o2 = MF(bv2, ap, o2);                                                    \
    o3 = MF(bv3, ap, o3); }

  LOADR(0); WRITES();
  __syncthreads();

  for (int kt = 0; kt < nt; kt++) {
    const bool pf = (kt + 1 < nt);
    if (pf) LOADR(kt + 1);

    f32x4 s0 = {0,0,0,0}, s1 = {0,0,0,0}, s2 = {0,0,0,0}, s3 = {0,0,0,0};
    QKSTEP(s0, 0) QKSTEP(s1, 1) QKSTEP(s2, 2) QKSTEP(s3, 3)

    const int kb = kt * 64;
    MASKN(s0, 0) MASKN(s1, 1) MASKN(s2, 2) MASKN(s3, 3)

    float vmax = fmaxf(fmaxf(fmaxf(s0[0], s0[1]), fmaxf(s0[2], s0[3])),
                       fmaxf(fmaxf(s1[0], s1[1]), fmaxf(s1[2], s1[3])));
    vmax = fmaxf(vmax, fmaxf(fmaxf(s2[0], s2[1]), fmaxf(s2[2], s2[3])));
    vmax = fmaxf(vmax, fmaxf(fmaxf(s3[0], s3[1]), fmaxf(s3[2], s3[3])));
    vmax = fmaxf(vmax, __shfl_xor(vmax, 16));
    vmax = fmaxf(vmax, __shfl_xor(vmax, 32));

    // defer-max (T13): skip O/l rescale when max grows by <= 8 (P <= e^8,
    // bf16-safe). Wave-uniform branch via __all.
    float nm = fmaxf(mrun, vmax);
    if (__all(nm - mrun <= 8.0f)) {
      nm = mrun;                       // keep old max
    } else {
      const float corr = __expf(mrun - nm);
      lsum *= corr;
      o0 *= corr; o1 *= corr; o2 *= corr; o3 *= corr;
      mrun = nm;
    }

    EXPN(s0) EXPN(s1) EXPN(s2) EXPN(s3)

    float rs = (s0[0] + s0[1]) + (s0[2] + s0[3]) + (s1[0] + s1[1]) + (s1[2] + s1[3])
             + (s2[0] + s2[1]) + (s2[2] + s2[3]) + (s3[0] + s3[1]) + (s3[2] + s3[3]);
    rs += __shfl_xor(rs, 16);
    rs += __shfl_xor(rs, 32);
    lsum += rs;

    PWRITE(s0, 0) PWRITE(s1, 1) PWRITE(s2, 2) PWRITE(s3, 3)

    PVSTEP(0) PVSTEP(1)

    if (pf) {
      __syncthreads();
      WRITES();
      __syncthreads();
    }
  }

  const float inv = 1.0f / lsum;
  const size_t rowoff = ((size_t)(bI * SEQ + qrow)) * DM + h * DH;
  #pragma unroll
  for (int df = 0; df < 4; df++) {
    const f32x4 ov = (df == 0) ? o0 : (df == 1) ? o1 : (df == 2) ? o2 : o3;
    #pragma unroll
    for (int jp = 0; jp < 2; jp++) {
      const float x0 = ov[2 * jp] * inv;
      const float x1 = ov[2 * jp + 1] * inv;
      const unsigned short h0 = f2bf(x0), h1 = f2bf(x1);
      const size_t col = rowoff + df * 16 + lh * 4 + 2 * jp;
      *(unsigned*)&AAh[col] = (unsigned)h0 | ((unsigned)h1 << 16);
    }
  }
#undef LOADR
#undef WRITES
#undef QKSTEP
#undef MASKN
#undef EXPN
#undef PWRITE
#undef PVSTEP
}

// ---------------------------------------------------------------------------
// ws layout (56 MB):
//   0MB: Xh(8) Xl(8)      -> after QKV consumed: AAh(8) from attn
//  16MB: Kh(8) Kl(8)
//  32MB: Vt(8)
//  40MB: WT 4x(hi 2MB + lo 2MB) = 16
// d_out: Qh(8) Ql(8) scratch, then final fp32 out (16).
// ---------------------------------------------------------------------------
extern "C" void kernel_launch(void* const* d_in, const int* in_sizes, int n_in,
                              void* d_out, int out_size, void* d_ws, size_t ws_size,
                              hipStream_t stream) {
  const float* x  = (const float*)d_in[0];
  const float* qw = (const float*)d_in[1];
  const float* kw = (const float*)d_in[2];
  const float* vw = (const float*)d_in[3];
  const float* ow = (const float*)d_in[4];

  char* ws = (char*)d_ws;
  ushort_t* Xh  = (ushort_t*)ws;
  ushort_t* Xl  = Xh + 4194304;
  ushort_t* AAh = Xh;                      // Xh dead after QKV gemm
  ushort_t* Kh  = (ushort_t*)(ws + (16u << 20));
  ushort_t* Kl  = Kh + 4194304;
  ushort_t* Vt  = (ushort_t*)(ws + (32u << 20));
  ushort_t* WT  = (ushort_t*)(ws + (40u << 20));
  ushort_t* Qh  = (ushort_t*)d_out;
  ushort_t* Ql  = Qh + 4194304;
  float*    out = (float*)d_out;

  split_f32<<<dim3(2048), dim3(256), 0, stream>>>(x, Xh, Xl, 524288);
  wtrans<<<dim3(16, 16, 4), dim3(256), 0, stream>>>(qw, kw, vw, ow, WT);
  gemm_qkv<<<dim3(8, 32, 3), dim3(256), 0, stream>>>(
      Xh, Xl, WT, Qh, Ql, Kh, Kl, Vt);
  attn_mfma<<<dim3(SEQ / 64, BATCH * NH), dim3(256), 0, stream>>>(
      Qh, Ql, Kh, Kl, Vt, AAh);
  gemm_out<<<dim3(16, 32), dim3(256), 0, stream>>>(AAh, WT, out);
}